// Round 1
// baseline (179.405 us; speedup 1.0000x reference)
//
#include <hip/hip_runtime.h>

// Problem constants
#define T_LEN 120
#define H 128
#define ROWS 16          // batch rows per block
#define XSTR 484         // padded x row stride (f32) to break LDS bank alignment
#define FC1_STRIDE 15360 // T*H

// workspace layout (bytes)
#define OFF_WHH   0u        // [512][128] bf16 = 131072
#define OFF_WXB   131072u   // [512][32]  bf16 = 32768 (W_ih cols 0-3, bias col 4)
#define OFF_FC1W  163840u   // [128][15360] bf16 = 3932160 (rows >=100 zero)
#define OFF_FC1B  4096000u  // [128] f32 (zero-padded)

typedef short short8 __attribute__((ext_vector_type(8)));   // 8 bf16 in 4 VGPRs
typedef float f32x4 __attribute__((ext_vector_type(4)));

__device__ __forceinline__ unsigned short f2bu(float f) {   // f32 -> bf16 (RNE)
  unsigned u = __builtin_bit_cast(unsigned, f);
  u += 0x7fffu + ((u >> 16) & 1u);
  return (unsigned short)(u >> 16);
}
__device__ __forceinline__ float fsig(float x) {
  return __builtin_amdgcn_rcpf(1.f + __builtin_amdgcn_exp2f(-1.4426950408889634f * x));
}
__device__ __forceinline__ float ftanh(float x) {
  return 1.f - 2.f * __builtin_amdgcn_rcpf(1.f + __builtin_amdgcn_exp2f(2.8853900817779268f * x));
}

// ---- one-time weight conversion kernels ----
__global__ void prep_small(const float* __restrict__ W_ih, const float* __restrict__ W_hh,
                           const float* __restrict__ b_ih, const float* __restrict__ b_hh,
                           const float* __restrict__ fc1_b, unsigned char* __restrict__ ws) {
  unsigned short* whh = (unsigned short*)(ws + OFF_WHH);
  unsigned short* wxb = (unsigned short*)(ws + OFF_WXB);
  float* fb = (float*)(ws + OFF_FC1B);
  int tid = blockIdx.x * blockDim.x + threadIdx.x;
  int nt = gridDim.x * blockDim.x;
  for (int i = tid; i < 512 * 128; i += nt) whh[i] = f2bu(W_hh[i]);
  for (int i = tid; i < 512 * 32; i += nt) {
    int j = i >> 5, k = i & 31;
    float v = 0.f;
    if (k < 4) v = W_ih[j * 4 + k];
    else if (k == 4) v = b_ih[j] + b_hh[j];
    wxb[i] = f2bu(v);
  }
  for (int i = tid; i < 128; i += nt) fb[i] = (i < 100) ? fc1_b[i] : 0.f;
}

__global__ void prep_fc1(const float* __restrict__ fc1_w, unsigned char* __restrict__ ws) {
  unsigned short* w = (unsigned short*)(ws + OFF_FC1W);
  int j = blockIdx.y;
  int c0 = (blockIdx.x * 256 + threadIdx.x) * 8;
  if (c0 >= FC1_STRIDE) return;
  short8 v = {0, 0, 0, 0, 0, 0, 0, 0};
  if (j < 100) {
    const float* src = fc1_w + j * FC1_STRIDE + c0;
#pragma unroll
    for (int e = 0; e < 8; ++e) ((unsigned short*)&v)[e] = f2bu(src[e]);
  }
  *(short8*)(w + j * FC1_STRIDE + c0) = v;
}

// ---- fused persistent kernel: LSTM recurrence + fc1 accumulation + fc2 + log_softmax ----
__global__ __launch_bounds__(512, 2)
void lstm_fused(const float* __restrict__ x, const float* __restrict__ h0,
                const float* __restrict__ c0, const float* __restrict__ fc2_w,
                const float* __restrict__ fc2_b, const unsigned char* __restrict__ ws,
                float* __restrict__ out) {
  __shared__ float x_stage[ROWS * XSTR];                 // x staged f32; reused as hid in epilogue
  __shared__ __align__(16) unsigned char h_lds[ROWS * H * 2];  // bf16 h, XOR-swizzled
  __shared__ __align__(16) float fc2w_s[1000];
  __shared__ float fc2b_s[10];
  __shared__ float logit_s[ROWS * 12];

  const int tid = threadIdx.x;
  const int w = tid >> 6;        // wave 0..7
  const int l = tid & 63;
  const int lq = l >> 4;         // lane quarter
  const int lc = l & 15;
  const int r0 = blockIdx.x * ROWS;
  const int hcol = w * 16 + lc;  // this lane's h/gate column

  const unsigned short* Whh = (const unsigned short*)(ws + OFF_WHH);
  const unsigned short* Wxb = (const unsigned short*)(ws + OFF_WXB);
  const unsigned short* FC1 = (const unsigned short*)(ws + OFF_FC1W);
  const float* FC1B = (const float*)(ws + OFF_FC1B);

  // stage x for this block's 16 rows: [16][480] f32 (padded stride 484)
  for (int i = tid; i < ROWS * 480; i += 512) {
    int r = i / 480;
    int cc = i - r * 480;
    x_stage[r * XSTR + cc] = x[(r0 + r) * 480 + cc];
  }
  // stage h0 -> bf16 swizzled: byte = r*256 + ((2c) ^ ((r&7)<<4))
  for (int e = tid * 2; e < ROWS * H; e += 1024) {
    int r = e >> 7, c = e & 127;
    unsigned u = (unsigned)f2bu(h0[(r0 + r) * H + c]) |
                 ((unsigned)f2bu(h0[(r0 + r) * H + c + 1]) << 16);
    *(unsigned*)(h_lds + r * 256 + ((2 * c) ^ ((r & 7) << 4))) = u;
  }
  // c0 into regs: lane owns rows lq*4+q, col hcol
  float c_reg[4];
#pragma unroll
  for (int q = 0; q < 4; ++q) c_reg[q] = c0[(r0 + lq * 4 + q) * H + hcol];

  // register-resident B fragments. Wave w owns gate tiles {w, 8+w, 16+w, 24+w}
  // (one tile per gate type, all at the same h column range -> in-register c update).
  short8 bhh[4][4], bxb[4];
#pragma unroll
  for (int g = 0; g < 4; ++g) {
    int n0 = (g * 8 + w) * 16;
#pragma unroll
    for (int kk = 0; kk < 4; ++kk)
      bhh[g][kk] = *(const short8*)(Whh + (n0 + lc) * H + kk * 32 + lq * 8);
    bxb[g] = *(const short8*)(Wxb + (n0 + lc) * 32 + lq * 8);
  }
  const unsigned short* fc1row = FC1 + (w * 16 + lc) * FC1_STRIDE;  // wave w = fc1 tile w
  f32x4 facc = {0.f, 0.f, 0.f, 0.f};

  __syncthreads();

  // initial A fragments (h0) ; A[m][k]: lane holds row lc, k = kk*32 + lq*8 + e
  short8 ha[4];
#pragma unroll
  for (int kk = 0; kk < 4; ++kk)
    ha[kk] = *(const short8*)(h_lds + lc * 256 + ((kk * 64 + lq * 16) ^ ((lc & 7) << 4)));

  // x A-fragment: A_x[16][32], cols 0-3 = x, col 4 = 1.0 (bias), rest 0 -> only lq==0 nonzero
  short8 xa = {0, 0, 0, 0, 0, 0, 0, 0};
  if (lq == 0) {
    const float* xr = &x_stage[lc * XSTR];
    xa[0] = (short)f2bu(xr[0]); xa[1] = (short)f2bu(xr[1]);
    xa[2] = (short)f2bu(xr[2]); xa[3] = (short)f2bu(xr[3]);
    xa[4] = (short)0x3f80;  // bf16(1.0)
  }

  const f32x4 zero4 = {0.f, 0.f, 0.f, 0.f};

  for (int t = 0; t < T_LEN; ++t) {
    // prefetch fc1_w B-frags for this t (used after 2 barriers -> latency hidden)
    const unsigned short* fp = fc1row + t * 128 + lq * 8;
    short8 fb0 = *(const short8*)(fp + 0);
    short8 fb1 = *(const short8*)(fp + 32);
    short8 fb2 = *(const short8*)(fp + 64);
    short8 fb3 = *(const short8*)(fp + 96);

    // gates = [x,1]@Wxb^T + h@Whh^T   (K = 32 + 128)
    f32x4 acc0 = __builtin_amdgcn_mfma_f32_16x16x32_bf16(xa, bxb[0], zero4, 0, 0, 0);
    f32x4 acc1 = __builtin_amdgcn_mfma_f32_16x16x32_bf16(xa, bxb[1], zero4, 0, 0, 0);
    f32x4 acc2 = __builtin_amdgcn_mfma_f32_16x16x32_bf16(xa, bxb[2], zero4, 0, 0, 0);
    f32x4 acc3 = __builtin_amdgcn_mfma_f32_16x16x32_bf16(xa, bxb[3], zero4, 0, 0, 0);
#pragma unroll
    for (int kk = 0; kk < 4; ++kk) {
      acc0 = __builtin_amdgcn_mfma_f32_16x16x32_bf16(ha[kk], bhh[0][kk], acc0, 0, 0, 0);
      acc1 = __builtin_amdgcn_mfma_f32_16x16x32_bf16(ha[kk], bhh[1][kk], acc1, 0, 0, 0);
      acc2 = __builtin_amdgcn_mfma_f32_16x16x32_bf16(ha[kk], bhh[2][kk], acc2, 0, 0, 0);
      acc3 = __builtin_amdgcn_mfma_f32_16x16x32_bf16(ha[kk], bhh[3][kk], acc3, 0, 0, 0);
    }

    // activations + state update, all in registers (i,f,g,o at same (row,col) per lane)
    float hval[4];
#pragma unroll
    for (int q = 0; q < 4; ++q) {
      float iv = fsig(acc0[q]);
      float fv = fsig(acc1[q]);
      float gv = ftanh(acc2[q]);
      float ov = fsig(acc3[q]);
      float cn = fv * c_reg[q] + iv * gv;
      c_reg[q] = cn;
      hval[q] = ov * ftanh(cn);
    }
    __syncthreads();  // A: all waves finished reading h_lds (prev step's frags)
#pragma unroll
    for (int q = 0; q < 4; ++q) {
      int r = lq * 4 + q;
      *(unsigned short*)(h_lds + r * 256 + ((2 * hcol) ^ ((r & 7) << 4))) = f2bu(hval[q]);
    }
    __syncthreads();  // B: h_t complete
#pragma unroll
    for (int kk = 0; kk < 4; ++kk)
      ha[kk] = *(const short8*)(h_lds + lc * 256 + ((kk * 64 + lq * 16) ^ ((lc & 7) << 4)));
    if (t + 1 < T_LEN && lq == 0) {
      const float* xr = &x_stage[lc * XSTR + (t + 1) * 4];
      xa[0] = (short)f2bu(xr[0]); xa[1] = (short)f2bu(xr[1]);
      xa[2] = (short)f2bu(xr[2]); xa[3] = (short)f2bu(xr[3]);
    }
    // fc1 partial: facc += h_t @ fc1_w[:, t*128 : t*128+128]^T
    facc = __builtin_amdgcn_mfma_f32_16x16x32_bf16(ha[0], fb0, facc, 0, 0, 0);
    facc = __builtin_amdgcn_mfma_f32_16x16x32_bf16(ha[1], fb1, facc, 0, 0, 0);
    facc = __builtin_amdgcn_mfma_f32_16x16x32_bf16(ha[2], fb2, facc, 0, 0, 0);
    facc = __builtin_amdgcn_mfma_f32_16x16x32_bf16(ha[3], fb3, facc, 0, 0, 0);
  }

  // ---- epilogue: bias+ReLU -> fc2 -> log_softmax ----
  for (int i = tid; i < 1000; i += 512) fc2w_s[i] = fc2_w[i];
  if (tid < 10) fc2b_s[tid] = fc2_b[tid];
  float bias = FC1B[hcol];
  __syncthreads();                 // everyone out of the loop; x_stage free
  float* hid = x_stage;            // [16][132] padded
#pragma unroll
  for (int q = 0; q < 4; ++q) {
    float v = facc[q] + bias;
    hid[(lq * 4 + q) * 132 + hcol] = v > 0.f ? v : 0.f;
  }
  __syncthreads();
  if (tid < 160) {
    int r = tid & 15, k = tid >> 4;   // lanes sharing k broadcast fc2w reads
    float a = fc2b_s[k];
#pragma unroll 4
    for (int j = 0; j < 100; ++j) a += hid[r * 132 + j] * fc2w_s[k * 100 + j];
    logit_s[r * 12 + k] = a;
  }
  __syncthreads();
  if (tid < 16) {
    int r = tid;
    float m = logit_s[r * 12];
#pragma unroll
    for (int k = 1; k < 10; ++k) m = fmaxf(m, logit_s[r * 12 + k]);
    float s = 0.f;
#pragma unroll
    for (int k = 0; k < 10; ++k)
      s += __builtin_amdgcn_exp2f(1.4426950408889634f * (logit_s[r * 12 + k] - m));
    float ls = __builtin_amdgcn_logf(s) * 0.6931471805599453f;
#pragma unroll
    for (int k = 0; k < 10; ++k)
      out[(r0 + r) * 10 + k] = logit_s[r * 12 + k] - m - ls;
  }
}

extern "C" void kernel_launch(void* const* d_in, const int* in_sizes, int n_in,
                              void* d_out, int out_size, void* d_ws, size_t ws_size,
                              hipStream_t stream) {
  const float* x     = (const float*)d_in[0];
  const float* h0    = (const float*)d_in[1];
  const float* c0    = (const float*)d_in[2];
  const float* W_ih  = (const float*)d_in[3];
  const float* W_hh  = (const float*)d_in[4];
  const float* b_ih  = (const float*)d_in[5];
  const float* b_hh  = (const float*)d_in[6];
  const float* fc1_w = (const float*)d_in[7];
  const float* fc1_b = (const float*)d_in[8];
  const float* fc2_w = (const float*)d_in[9];
  const float* fc2_b = (const float*)d_in[10];
  float* out = (float*)d_out;
  unsigned char* ws = (unsigned char*)d_ws;

  prep_small<<<64, 256, 0, stream>>>(W_ih, W_hh, b_ih, b_hh, fc1_b, ws);
  prep_fc1<<<dim3(8, 128), 256, 0, stream>>>(fc1_w, ws);
  lstm_fused<<<256, 512, 0, stream>>>(x, h0, c0, fc2_w, fc2_b, ws, out);
}

// Round 2
// 151.045 us; speedup vs baseline: 1.1878x; 1.1878x over previous
//
#include <hip/hip_runtime.h>

// Problem constants
#define T_LEN 120
#define H 128
#define ROWS 16          // batch rows per block
#define XSTR 484         // padded x row stride (f32)
#define FC1_STRIDE 15360 // T*H

// workspace layout (bytes)
#define OFF_WHH   0u        // [512][128] bf16, pre-scaled by gate constant
#define OFF_WXB   131072u   // [512][32]  bf16 (W_ih cols 0-3, bias col 4), pre-scaled
#define OFF_FC1W  163840u   // [128][15360] bf16 (rows >=100 zero)
#define OFF_FC1B  4096000u  // [128] f32 (zero-padded)

typedef short short8 __attribute__((ext_vector_type(8)));   // 8 bf16 in 4 VGPRs
typedef float f32x4 __attribute__((ext_vector_type(4)));

#define L2E 1.4426950408889634f
// swizzle nibble: rows {q,q+4,q+8,q+12} -> XOR set {q, q^4, q^2, q^6} (distinct bank groups)
#define SWZ(r) (((((r) & 7) ^ (((r) >> 3) << 1))) << 4)

__device__ __forceinline__ unsigned short f2bu(float f) {   // f32 -> bf16 (RNE)
  unsigned u = __builtin_bit_cast(unsigned, f);
  u += 0x7fffu + ((u >> 16) & 1u);
  return (unsigned short)(u >> 16);
}
__device__ __forceinline__ float gate_scale(int row) {
  // rows 0-127: i, 128-255: f, 256-383: g, 384-511: o
  return ((row >> 7) == 2) ? 2.0f * L2E : -L2E;
}

// ---- one-time weight conversion (single launch) ----
__global__ void prep_all(const float* __restrict__ W_ih, const float* __restrict__ W_hh,
                         const float* __restrict__ b_ih, const float* __restrict__ b_hh,
                         const float* __restrict__ fc1_w, const float* __restrict__ fc1_b,
                         unsigned char* __restrict__ ws) {
  if (blockIdx.x < 1024) {
    // fc1_w -> bf16, 128 padded rows x 15360
    unsigned short* w = (unsigned short*)(ws + OFF_FC1W);
    int j = blockIdx.x >> 3;
    int c0 = ((blockIdx.x & 7) * 256 + threadIdx.x) * 8;
    if (c0 >= FC1_STRIDE) return;
    short8 v = {0, 0, 0, 0, 0, 0, 0, 0};
    if (j < 100) {
      const float* src = fc1_w + j * FC1_STRIDE + c0;
#pragma unroll
      for (int e = 0; e < 8; ++e) ((unsigned short*)&v)[e] = f2bu(src[e]);
    }
    *(short8*)(w + j * FC1_STRIDE + c0) = v;
  } else {
    unsigned short* whh = (unsigned short*)(ws + OFF_WHH);
    unsigned short* wxb = (unsigned short*)(ws + OFF_WXB);
    float* fb = (float*)(ws + OFF_FC1B);
    int tid = (blockIdx.x - 1024) * 256 + threadIdx.x;
    const int nt = 8 * 256;
    for (int i = tid; i < 512 * 128; i += nt) {
      int row = i >> 7;
      whh[i] = f2bu(W_hh[i] * gate_scale(row));
    }
    for (int i = tid; i < 512 * 32; i += nt) {
      int j = i >> 5, k = i & 31;
      float s = gate_scale(j);
      float v = 0.f;
      if (k < 4) v = W_ih[j * 4 + k] * s;
      else if (k == 4) v = (b_ih[j] + b_hh[j]) * s;
      wxb[i] = f2bu(v);
    }
    for (int i = tid; i < 128; i += nt) fb[i] = (i < 100) ? fc1_b[i] : 0.f;
  }
}

// ---- fused persistent kernel ----
__global__ __launch_bounds__(512, 2)
void lstm_fused(const float* __restrict__ x, const float* __restrict__ h0,
                const float* __restrict__ c0, const float* __restrict__ fc2_w,
                const float* __restrict__ fc2_b, const unsigned char* __restrict__ ws,
                float* __restrict__ out) {
  __shared__ float x_stage[ROWS * XSTR];                        // reused as hid in epilogue
  __shared__ __align__(16) unsigned char h_lds[2 * ROWS * 256]; // double-buffered bf16 h
  __shared__ __align__(16) float fc2w_s[1000];
  __shared__ float fc2b_s[10];
  __shared__ float logit_s[ROWS * 12];

  const int tid = threadIdx.x;
  const int w = tid >> 6;
  const int l = tid & 63;
  const int lq = l >> 4;
  const int lc = l & 15;
  const int r0 = blockIdx.x * ROWS;
  const int hcol = w * 16 + lc;

  const unsigned short* Whh = (const unsigned short*)(ws + OFF_WHH);
  const unsigned short* Wxb = (const unsigned short*)(ws + OFF_WXB);
  const unsigned short* FC1 = (const unsigned short*)(ws + OFF_FC1W);
  const float* FC1B = (const float*)(ws + OFF_FC1B);

  // stage x: [16][480] f32 (stride 484)
  for (int i = tid; i < ROWS * 480; i += 512) {
    int r = i / 480;
    int cc = i - r * 480;
    x_stage[r * XSTR + cc] = x[(r0 + r) * 480 + cc];
  }
  // stage h0 -> buffer 1 (loop t=0 writes buffer 0)
  for (int e = tid * 2; e < ROWS * H; e += 1024) {
    int r = e >> 7, c = e & 127;
    unsigned u = (unsigned)f2bu(h0[(r0 + r) * H + c]) |
                 ((unsigned)f2bu(h0[(r0 + r) * H + c + 1]) << 16);
    *(unsigned*)(h_lds + 4096 + r * 256 + ((2 * c) ^ SWZ(r))) = u;
  }
  float c_reg[4];
#pragma unroll
  for (int q = 0; q < 4; ++q) c_reg[q] = c0[(r0 + lq * 4 + q) * H + hcol];

  // register-resident B fragments; wave w owns gate tiles {w, 8+w, 16+w, 24+w}
  short8 bhh[4][4], bxb[4];
#pragma unroll
  for (int g = 0; g < 4; ++g) {
    int n0 = (g * 8 + w) * 16;
#pragma unroll
    for (int kk = 0; kk < 4; ++kk)
      bhh[g][kk] = *(const short8*)(Whh + (n0 + lc) * H + kk * 32 + lq * 8);
    bxb[g] = *(const short8*)(Wxb + (n0 + lc) * 32 + lq * 8);
  }
  const unsigned short* fc1row = FC1 + (w * 16 + lc) * FC1_STRIDE;
  f32x4 facc = {0.f, 0.f, 0.f, 0.f};

  __syncthreads();

  // initial A fragments from h0 (buffer 1)
  short8 ha[4];
#pragma unroll
  for (int kk = 0; kk < 4; ++kk)
    ha[kk] = *(const short8*)(h_lds + 4096 + lc * 256 + ((kk * 64 + lq * 16) ^ SWZ(lc)));

  // x A-fragment for t=0: cols 0-3 = x, col 4 = 1.0 (bias), rest 0
  short8 xa = {0, 0, 0, 0, 0, 0, 0, 0};
  if (lq == 0) {
    const float* xr = &x_stage[lc * XSTR];
    xa[0] = (short)f2bu(xr[0]); xa[1] = (short)f2bu(xr[1]);
    xa[2] = (short)f2bu(xr[2]); xa[3] = (short)f2bu(xr[3]);
    xa[4] = (short)0x3f80;
  }

  const f32x4 zero4 = {0.f, 0.f, 0.f, 0.f};
  // x-part of gates, precomputed one step ahead
  f32x4 accX0 = __builtin_amdgcn_mfma_f32_16x16x32_bf16(xa, bxb[0], zero4, 0, 0, 0);
  f32x4 accX1 = __builtin_amdgcn_mfma_f32_16x16x32_bf16(xa, bxb[1], zero4, 0, 0, 0);
  f32x4 accX2 = __builtin_amdgcn_mfma_f32_16x16x32_bf16(xa, bxb[2], zero4, 0, 0, 0);
  f32x4 accX3 = __builtin_amdgcn_mfma_f32_16x16x32_bf16(xa, bxb[3], zero4, 0, 0, 0);

  for (int t = 0; t < T_LEN; ++t) {
    // prefetch fc1_w B-frags for slice t (stays in flight across the raw barrier)
    const unsigned short* fp = fc1row + t * 128 + lq * 8;
    short8 fb0 = *(const short8*)(fp + 0);
    short8 fb1 = *(const short8*)(fp + 32);
    short8 fb2 = *(const short8*)(fp + 64);
    short8 fb3 = *(const short8*)(fp + 96);

    // gates(t): start from precomputed x-part, add h_{t-1}@Whh^T (4 dep MFMAs/gate)
    f32x4 acc0 = accX0, acc1 = accX1, acc2 = accX2, acc3 = accX3;
#pragma unroll
    for (int kk = 0; kk < 4; ++kk) {
      acc0 = __builtin_amdgcn_mfma_f32_16x16x32_bf16(ha[kk], bhh[0][kk], acc0, 0, 0, 0);
      acc1 = __builtin_amdgcn_mfma_f32_16x16x32_bf16(ha[kk], bhh[1][kk], acc1, 0, 0, 0);
      acc2 = __builtin_amdgcn_mfma_f32_16x16x32_bf16(ha[kk], bhh[2][kk], acc2, 0, 0, 0);
      acc3 = __builtin_amdgcn_mfma_f32_16x16x32_bf16(ha[kk], bhh[3][kk], acc3, 0, 0, 0);
    }

    // rebuild xa for t+1 and precompute its gate contribution (off critical path)
    if (t + 1 < T_LEN && lq == 0) {
      const float* xr = &x_stage[lc * XSTR + (t + 1) * 4];
      xa[0] = (short)f2bu(xr[0]); xa[1] = (short)f2bu(xr[1]);
      xa[2] = (short)f2bu(xr[2]); xa[3] = (short)f2bu(xr[3]);
    }
    accX0 = __builtin_amdgcn_mfma_f32_16x16x32_bf16(xa, bxb[0], zero4, 0, 0, 0);
    accX1 = __builtin_amdgcn_mfma_f32_16x16x32_bf16(xa, bxb[1], zero4, 0, 0, 0);
    accX2 = __builtin_amdgcn_mfma_f32_16x16x32_bf16(xa, bxb[2], zero4, 0, 0, 0);
    accX3 = __builtin_amdgcn_mfma_f32_16x16x32_bf16(xa, bxb[3], zero4, 0, 0, 0);

    // activations (weights pre-scaled: exp2 direct; paired reciprocals: 5 exp + 3 rcp)
    float hval[4];
#pragma unroll
    for (int q = 0; q < 4; ++q) {
      float ea = __builtin_amdgcn_exp2f(acc0[q]);           // e^{-xi}
      float eb = __builtin_amdgcn_exp2f(acc1[q]);           // e^{-xf}
      float ec = __builtin_amdgcn_exp2f(acc2[q]);           // e^{2xg}
      float ed = __builtin_amdgcn_exp2f(acc3[q]);           // e^{-xo}
      float a = 1.f + ea, b = 1.f + eb, d = 1.f + ec, e = 1.f + ed;
      float rab = __builtin_amdgcn_rcpf(a * b);
      float rde = __builtin_amdgcn_rcpf(d * e);
      float iv = b * rab;                 // sigmoid(xi)
      float fv = a * rab;                 // sigmoid(xf)
      float gv = 1.f - 2.f * (e * rde);   // tanh(xg)
      float ov = d * rde;                 // sigmoid(xo)
      float cn = fv * c_reg[q] + iv * gv;
      c_reg[q] = cn;
      float et = __builtin_amdgcn_exp2f(2.8853900817779268f * cn);
      hval[q] = ov * (1.f - 2.f * __builtin_amdgcn_rcpf(1.f + et));
    }

    // store h_t into buffer t&1 (no pre-write barrier needed: other buffer was read)
    unsigned char* hw = h_lds + (t & 1) * 4096;
#pragma unroll
    for (int q = 0; q < 4; ++q) {
      int r = lq * 4 + q;
      *(unsigned short*)(hw + r * 256 + ((2 * hcol) ^ SWZ(r))) = f2bu(hval[q]);
    }

    asm volatile("s_waitcnt lgkmcnt(0)" ::: "memory");
    __builtin_amdgcn_s_barrier();
    asm volatile("" ::: "memory");

    // read h_t fragments; fc1 partial (off next step's critical path)
#pragma unroll
    for (int kk = 0; kk < 4; ++kk)
      ha[kk] = *(const short8*)(hw + lc * 256 + ((kk * 64 + lq * 16) ^ SWZ(lc)));
    facc = __builtin_amdgcn_mfma_f32_16x16x32_bf16(ha[0], fb0, facc, 0, 0, 0);
    facc = __builtin_amdgcn_mfma_f32_16x16x32_bf16(ha[1], fb1, facc, 0, 0, 0);
    facc = __builtin_amdgcn_mfma_f32_16x16x32_bf16(ha[2], fb2, facc, 0, 0, 0);
    facc = __builtin_amdgcn_mfma_f32_16x16x32_bf16(ha[3], fb3, facc, 0, 0, 0);
  }

  // ---- epilogue: bias+ReLU -> fc2 -> log_softmax ----
  for (int i = tid; i < 1000; i += 512) fc2w_s[i] = fc2_w[i];
  if (tid < 10) fc2b_s[tid] = fc2_b[tid];
  float bias = FC1B[hcol];
  __syncthreads();                 // everyone out of the loop; x_stage free
  float* hid = x_stage;            // [16][132] padded
#pragma unroll
  for (int q = 0; q < 4; ++q) {
    float v = facc[q] + bias;
    hid[(lq * 4 + q) * 132 + hcol] = v > 0.f ? v : 0.f;
  }
  __syncthreads();
  if (tid < 160) {
    int r = tid & 15, k = tid >> 4;
    float a = fc2b_s[k];
#pragma unroll 4
    for (int j = 0; j < 100; ++j) a += hid[r * 132 + j] * fc2w_s[k * 100 + j];
    logit_s[r * 12 + k] = a;
  }
  __syncthreads();
  if (tid < 16) {
    int r = tid;
    float m = logit_s[r * 12];
#pragma unroll
    for (int k = 1; k < 10; ++k) m = fmaxf(m, logit_s[r * 12 + k]);
    float s = 0.f;
#pragma unroll
    for (int k = 0; k < 10; ++k)
      s += __builtin_amdgcn_exp2f(L2E * (logit_s[r * 12 + k] - m));
    float ls = __builtin_amdgcn_logf(s) * 0.6931471805599453f;
#pragma unroll
    for (int k = 0; k < 10; ++k)
      out[(r0 + r) * 10 + k] = logit_s[r * 12 + k] - m - ls;
  }
}

extern "C" void kernel_launch(void* const* d_in, const int* in_sizes, int n_in,
                              void* d_out, int out_size, void* d_ws, size_t ws_size,
                              hipStream_t stream) {
  const float* x     = (const float*)d_in[0];
  const float* h0    = (const float*)d_in[1];
  const float* c0    = (const float*)d_in[2];
  const float* W_ih  = (const float*)d_in[3];
  const float* W_hh  = (const float*)d_in[4];
  const float* b_ih  = (const float*)d_in[5];
  const float* b_hh  = (const float*)d_in[6];
  const float* fc1_w = (const float*)d_in[7];
  const float* fc1_b = (const float*)d_in[8];
  const float* fc2_w = (const float*)d_in[9];
  const float* fc2_b = (const float*)d_in[10];
  float* out = (float*)d_out;
  unsigned char* ws = (unsigned char*)d_ws;

  prep_all<<<1032, 256, 0, stream>>>(W_ih, W_hh, b_ih, b_hh, fc1_w, fc1_b, ws);
  lstm_fused<<<256, 512, 0, stream>>>(x, h0, c0, fc2_w, fc2_b, ws, out);
}